// Round 20
// baseline (95.379 us; speedup 1.0000x reference)
//
#include <hip/hip_runtime.h>
#include <hip/hip_fp16.h>

// HybridLoss: 0.8*MSE + 0.2*(1-SSIM), SSIM via separable 11x11 Gaussian (sigma=1.5)
// Input: pred, target f32 (32,3,512,512). Output: scalar f32.
// r19 structure (proven 90.1 us): 64x128 strip, 256 thr, CHUNK=16, BUF=26, async
// raw staging via global_load_lds, folded wraps, fp16 s_q, packed-fp16 convs.
// r20: DMA gets a FULL CHUNK of latency cover (r17-r19 stall grew 17.6->27.9 us
// as VALU shrank -> fixed DMA-at-barrier latency exposed):
//   - raw pixel DOUBLE buffer: DMA k+1 -> raw[(k+1)&1] while hconv k reads raw[k&1]
//   - DMA issued at PHASE-A start (cover = hconv + barrier A + vconv)
//   - barrier A is LGKM-ONLY (asm s_waitcnt lgkmcnt(0) + s_barrier): __syncthreads
//     would drain vmcnt(0) and kill the pipeline (global_load_lds is vmcnt-tracked)
//   - barrier B stays __syncthreads: its vmcnt(0) drain publishes the raw buffer
// LDS 24->34.2 KB (4 blocks/CU, was 6) — betting stall removal beats occupancy.
// REFUTED: f32 pack (r12/13), reg prefetch (r9/10), min-waves>=6 (r5/7 spill).

#define W 512
#define H 512
#define NIMG 96
#define TX 64
#define CHUNK 16
#define STRIP 128
#define NITER 8            // STRIP/CHUNK
#define BUF 26             // s_q circular rows
#define PADH 66            // uint2 row stride: 528 B -> 4-way b64 floor
#define NSLOT 128
#define RAWB 10240         // raw staging PER BUFFER: 2 tensors * 16 rows * 320 B

typedef __fp16 h2 __attribute__((ext_vector_type(2)));   // matches cvt_pkrtz return

// symmetric gaussian: gw[k] == gwu[k<6 ? k : 10-k], k compile-time when unrolled
#define GW(k)  gwu[(k) < 6 ? (k) : 10 - (k)]
#define GWH(k) gwh[(k) < 6 ? (k) : 10 - (k)]

#define GLL(sp, dp) __builtin_amdgcn_global_load_lds(                         \
    (const __attribute__((address_space(1))) void*)(sp),                      \
    (__attribute__((address_space(3))) void*)(dp), 16, 0, 0)

__global__ void hybrid_init(double* __restrict__ ws) {
    int t = threadIdx.x;
    if (t < 2 * NSLOT) ws[t] = 0.0;
}

__global__ __launch_bounds__(256, 4) void hybrid_main(
    const float* __restrict__ pred, const float* __restrict__ targ,
    double* __restrict__ ws)
{
    __shared__ uint2 s_q[BUF][PADH];                 // 13728 B: hconv results (fp16 x4)
    __shared__ __align__(16) char s_raw[2][RAWB];    // 20480 B: raw pixels, dbuf

    const int tid = threadIdx.x;
    const float* __restrict__ pp = pred + (size_t)blockIdx.z * (H * W);
    const float* __restrict__ tp = targ + (size_t)blockIdx.z * (H * W);
    const int xbase = blockIdx.x * TX;
    const int Y0 = blockIdx.y * STRIP;
    const int xb8 = xbase - 8;         // raw window = [xb8, xb8+80)

    // Normalized 1D Gaussian, 6 unique weights (symmetric), f32 like ref
    float gwu[6];
    __fp16 gwh[6];
    {
        float s = 0.f;
#pragma unroll
        for (int k = 0; k < 6; ++k) {
            float d = (float)(k - 5);
            gwu[k] = expf(-d * d / 4.5f);   // 2*sigma^2 = 4.5
            s += (k < 5) ? 2.f * gwu[k] : gwu[k];
        }
        float inv = 1.f / s;
#pragma unroll
        for (int k = 0; k < 6; ++k) { gwu[k] *= inv; gwh[k] = (__fp16)gwu[k]; }
    }

    // explicit ranges so clang's value-range analysis folds wrap checks
    const int hrow_i = (tid >> 4) & 15;   // 0..15 : hconv row-in-chunk
    const int g      = tid & 15;          // 4-col group
    const int c0     = g * 4;
    const int A0     = xbase + c0 - 8;    // 20-px window [A0, A0+20)
    const bool inX   = (A0 >= 0) && (A0 + 20 <= W);

    const int wv     = (tid >> 6) & 3;    // wave 0..3
    const int cc     = tid & 63;          // vconv column
    const int lane16 = (tid & 63) * 16;

    // slow-path needed only where reads could run past the allocation end
    const bool tb = ((int)blockIdx.z == NIMG - 1) && ((int)blockIdx.y == (H / STRIP) - 1);

    float mse_local = 0.f, ssim_local = 0.f;

    // ---- chunk-invariant DMA addressing (per wave: m = wv, wv+4, [wv+8]) ----
    auto mksrc = [&](int m, const float*& sp) {
        const int t  = (m >= 5);
        const int mm = m - 5 * t;
        const int oo = mm * 1024 + lane16;
        const int r  = oo / 320;
        const int cb = oo - r * 320;
        int col = xb8 + (cb >> 2);
        col = col < 0 ? 0 : (col > W - 4 ? W - 4 : col);
        sp = (t ? tp : pp) + (size_t)(Y0 + 5 + r) * W + col;
    };
    const float *sA, *sB, *sC = nullptr;
    mksrc(wv, sA);
    mksrc(wv + 4, sB);
    const bool hasC = (wv + 8) < 10;
    if (hasC) mksrc(wv + 8, sC);
    const int oA = wv * 1024, oB = (wv + 4) * 1024, oC = (wv + 8) * 1024;

    auto issue_fast = [&](int par) {   // advance-only: 2-3 DMA + ptr bumps
        GLL(sA, &s_raw[par][oA]); sA += CHUNK * W;
        GLL(sB, &s_raw[par][oB]); sB += CHUNK * W;
        if (hasC) { GLL(sC, &s_raw[par][oC]); sC += CHUNK * W; }
    };

    auto issue_slow = [&](int kc, int par) {  // y-clamped path, tail blocks only
        const int gybase = Y0 + 5 + CHUNK * kc;
#pragma unroll
        for (int m0 = 0; m0 < 12; m0 += 4) {
            const int m = wv + m0;
            if (m < 10) {
                const int t  = (m >= 5);
                const int oo = (m - 5 * t) * 1024 + lane16;
                const int r  = oo / 320;
                const int cb = oo - r * 320;
                int gy = gybase + r; if (gy > H - 1) gy = H - 1;
                int col = xb8 + (cb >> 2);
                col = col < 0 ? 0 : (col > W - 4 ? W - 4 : col);
                const float* src = (t ? tp : pp) + gy * W + col;
                GLL(src, &s_raw[par][m * 1024]);
            }
        }
    };

    // ---- read this thread's 20-px window from a raw buffer (+ x-edge masks) ----
    auto read_staged = [&](const char* base, float* xa, float* ya) {
#pragma unroll
        for (int v = 0; v < 5; ++v) {
            const int off = hrow_i * 320 + (g + v) * 16;
            float4 a = *(const float4*)&base[off];
            float4 b = *(const float4*)&base[RAWB / 2 + off];
            xa[4*v+0]=a.x; xa[4*v+1]=a.y; xa[4*v+2]=a.z; xa[4*v+3]=a.w;
            ya[4*v+0]=b.x; ya[4*v+1]=b.y; ya[4*v+2]=b.z; ya[4*v+3]=b.w;
        }
        if (!inX) {                      // only blocks x=0,7 ever diverge here
#pragma unroll
            for (int j = 0; j < 20; ++j) {
                if ((unsigned)(A0 + j) >= (unsigned)W) { xa[j] = 0.f; ya[j] = 0.f; }
            }
        }
    };

    // ---- MSE (raw f32) + clip + horizontal 11-tap in PACKED FP16 -> s_q ----
    auto hconv_store = [&](const float* xa, const float* ya, int slot, bool own) {
        if (own) {
#pragma unroll
            for (int c = 0; c < 4; ++c) {
                float d = xa[8 + c] - ya[8 + c];
                mse_local = fmaf(d, d, mse_local);
            }
        }
        h2 a01[4], a2x[4];               // (mu_x,mu_y), (E[x2+y2],E[xy]) pairs
#pragma unroll
        for (int i = 0; i < 4; ++i) {
            a01[i] = (h2)(__fp16)0.f;
            a2x[i] = (h2)(__fp16)0.f;
        }
#pragma unroll
        for (int j = 0; j < 14; ++j) {        // window positions 3..16
            float cx = __builtin_amdgcn_fmed3f(xa[3 + j], 0.f, 1.f);
            float yv = ya[3 + j];
            float s2 = fmaf(yv, yv, cx * cx); // x^2 + y^2
            float xy = cx * yv;
            h2 p0 = __builtin_amdgcn_cvt_pkrtz(cx, yv);
            h2 p1 = __builtin_amdgcn_cvt_pkrtz(s2, xy);
#pragma unroll
            for (int i = 0; i < 4; ++i) {
                int k = j - i;
                if (k >= 0 && k < 11) {
                    __fp16 w = GWH(k);
                    h2 w2; w2.x = w; w2.y = w;
                    a01[i] = w2 * p0 + a01[i];   // v_pk_fma_f16
                    a2x[i] = w2 * p1 + a2x[i];   // v_pk_fma_f16
                }
            }
        }
#pragma unroll
        for (int i = 0; i < 4; ++i) {
            uint2 u;
            u.x = __builtin_bit_cast(unsigned int, a01[i]);
            u.y = __builtin_bit_cast(unsigned int, a2x[i]);
            s_q[slot][c0 + i] = u;                              // ds_write_b64
        }
    };

    // ---- Prologue: DMA chunk 0 -> raw[0]; direct-load hconv of ext rows 0..9 ----
    if (tb) issue_slow(0, 0); else issue_fast(0);
    if (hrow_i < 10) {
        float xa[20], ya[20];
        const int gy = Y0 - 5 + hrow_i;
        if (gy >= 0 && gy < H) {
            const float* __restrict__ px = pp + (size_t)gy * W;
            const float* __restrict__ py = tp + (size_t)gy * W;
            if (inX) {
                const float4* qx = (const float4*)(px + A0);
                const float4* qy = (const float4*)(py + A0);
#pragma unroll
                for (int v = 0; v < 5; ++v) {
                    float4 a = qx[v], b = qy[v];
                    xa[4*v+0]=a.x; xa[4*v+1]=a.y; xa[4*v+2]=a.z; xa[4*v+3]=a.w;
                    ya[4*v+0]=b.x; ya[4*v+1]=b.y; ya[4*v+2]=b.z; ya[4*v+3]=b.w;
                }
            } else {
#pragma unroll
                for (int j = 0; j < 20; ++j) {
                    int col = A0 + j;
                    bool ok = (col >= 0) && (col < W);
                    xa[j] = ok ? px[col] : 0.f;
                    ya[j] = ok ? py[col] : 0.f;
                }
            }
        } else {
#pragma unroll
            for (int j = 0; j < 20; ++j) { xa[j] = 0.f; ya[j] = 0.f; }
        }
        hconv_store(xa, ya, hrow_i, hrow_i >= 5);
    }
    __syncthreads();   // drains chunk-0 DMA (vmcnt); prologue s_q visible

    const float C1 = 1e-4f, C2 = 9e-4f;

#pragma unroll
    for (int k = 0; k < NITER; ++k) {
        // ---- phase A: issue DMA k+1 -> raw[(k+1)&1]; hconv k from raw[k&1] ----
        if (k + 1 < NITER) {
            if (tb) issue_slow(k + 1, (k + 1) & 1); else issue_fast((k + 1) & 1);
        }
        {
            const int ext = CHUNK * k + 10 + hrow_i;
            const int gy  = Y0 - 5 + ext;                // >= 5, can exceed H-1
            const int hb  = (10 + CHUNK * k) % BUF;      // compile-time
            int slot;
            if (hb + 15 >= BUF) {                        // compile-time guard
                slot = hb + hrow_i; if (slot >= BUF) slot -= BUF;
            } else {
                slot = hb + hrow_i;                      // provably in range
            }
            if (gy < H) {
                float xa[20], ya[20];
                read_staged(s_raw[k & 1], xa, ya);
                hconv_store(xa, ya, slot, ext <= STRIP + 4);
            } else {                                     // OOB row: zeros, no conv
                uint2 z; z.x = 0u; z.y = 0u;
#pragma unroll
                for (int i = 0; i < 4; ++i) s_q[slot][c0 + i] = z;
            }
        }
        // barrier A: LGKM-ONLY (publishes s_q; does NOT drain the in-flight DMA)
        asm volatile("s_waitcnt lgkmcnt(0)" ::: "memory");
        __builtin_amdgcn_s_barrier();
        __builtin_amdgcn_sched_barrier(0);

        // ---- phase B: vconv k (reads s_q ext 16k .. 16k+25), packed fp16 ----
        {
            const int vb = (CHUNK * k) % BUF;            // compile-time
            const int r4 = 4 * wv;                       // 0,4,8,12 (range known)
            h2 a01[4], a2x[4];           // (mu_x,mu_y), (E[x2+y2],E[xy]) pairs
#pragma unroll
            for (int i = 0; i < 4; ++i) {
                a01[i] = (h2)(__fp16)0.f;
                a2x[i] = (h2)(__fp16)0.f;
            }
#pragma unroll
            for (int j = 0; j < 14; ++j) {
                const int sj = vb + j;                   // compile-time
                int s;
                if (sj + 12 >= BUF) {                    // compile-time guard
                    s = sj + r4; if (s >= BUF) s -= BUF;
                } else {
                    s = sj + r4;                         // provably in range
                }
                uint2 u = s_q[s][cc];                    // ds_read_b64
                h2 lo = __builtin_bit_cast(h2, u.x);
                h2 hi = __builtin_bit_cast(h2, u.y);
#pragma unroll
                for (int i = 0; i < 4; ++i) {
                    int kk = j - i;
                    if (kk >= 0 && kk < 11) {
                        __fp16 w = GWH(kk);
                        h2 w2; w2.x = w; w2.y = w;
                        a01[i] = w2 * lo + a01[i];       // v_pk_fma_f16
                        a2x[i] = w2 * hi + a2x[i];       // v_pk_fma_f16
                    }
                }
            }
#pragma unroll
            for (int i = 0; i < 4; ++i) {
                float mux = (float)a01[i].x, muy = (float)a01[i].y;
                float es  = (float)a2x[i].x, exy = (float)a2x[i].y;
                float mu_x2 = mux * mux, mu_y2 = muy * muy, mu_xy = mux * muy;
                float ssum = es - mu_x2 - mu_y2;         // sigma_x2 + sigma_y2
                float sxy  = exy - mu_xy;
                float num = (2.f*mu_xy + C1) * (2.f*sxy + C2);
                float den = (mu_x2 + mu_y2 + C1) * (ssum + C2);
                ssim_local = fmaf(num, __builtin_amdgcn_rcpf(den), ssim_local);
            }
        }
        __syncthreads();   // barrier B: drains vmcnt (publishes raw[(k+1)&1]);
                           // also guards s_q overwrite (hconv k+1) vs vconv k reads
    }

    // ---- Per-wave reduction + spread f64 atomics ----
    float m = mse_local, s2 = ssim_local;
#pragma unroll
    for (int off = 32; off; off >>= 1) {
        m  += __shfl_down(m, off);
        s2 += __shfl_down(s2, off);
    }
    if ((tid & 63) == 0) {
        int flat = blockIdx.x + 8 * (blockIdx.y + 4 * blockIdx.z);
        int slot = (flat * 4 + wv) & (NSLOT - 1);
        atomicAdd(&ws[slot], (double)m);
        atomicAdd(&ws[NSLOT + slot], (double)s2);
    }
}

__global__ void hybrid_fin(const double* __restrict__ ws, float* __restrict__ out) {
    int t = threadIdx.x;  // 64 threads
    double m = ws[t] + ws[t + 64];
    double s = ws[NSLOT + t] + ws[NSLOT + t + 64];
#pragma unroll
    for (int off = 32; off; off >>= 1) {
        m += __shfl_down(m, off);
        s += __shfl_down(s, off);
    }
    if (t == 0) {
        const double N = (double)NIMG * H * W;
        double mse  = m / N;
        double ssim = s / N;
        out[0] = (float)(0.8 * mse + 0.2 * (1.0 - ssim));
    }
}

extern "C" void kernel_launch(void* const* d_in, const int* in_sizes, int n_in,
                              void* d_out, int out_size, void* d_ws, size_t ws_size,
                              hipStream_t stream) {
    const float* pred = (const float*)d_in[0];
    const float* targ = (const float*)d_in[1];
    double* ws = (double*)d_ws;
    float* out = (float*)d_out;

    hybrid_init<<<1, 256, 0, stream>>>(ws);
    dim3 grid(W / TX, H / STRIP, NIMG);
    hybrid_main<<<grid, dim3(256), 0, stream>>>(pred, targ, ws);
    hybrid_fin<<<1, 64, 0, stream>>>(ws, out);
}

// Round 21
// 90.591 us; speedup vs baseline: 1.0528x; 1.0528x over previous
//
#include <hip/hip_runtime.h>
#include <hip/hip_fp16.h>

// HybridLoss: 0.8*MSE + 0.2*(1-SSIM), SSIM via separable 11x11 Gaussian (sigma=1.5)
// Input: pred, target f32 (32,3,512,512). Output: scalar f32.
// FINAL (r19, proven 90.1 us = 3.03x over r1 baseline): 64x128 strip, 256 thr,
// CHUNK=16, BUF=26, async raw staging via global_load_lds (single buffer, DMA
// issued at phase-B start — cover = vconv + cross-block wave overlap at 6
// blocks/CU), folded circular wraps, fp16 s_q plane, packed-fp16 both convs
// (v_pk_fma_f16; operands pair-adjacent with zero movs).
// REFUTED this session: f32 pack (r12/13: mov overhead + halved ILP), register
// prefetch (r9: compiler sinks loads; r10: VGPR 148 blowup), min-waves>=6
// (r5/r7: VGPR clamp -> scratch spill), CHUNK=32/512thr (r8: barrier convoy),
// raw LDS dbuf + lgkm-only barrier (r20: 6->4 blocks/CU costs more than the
// DMA-latency save). SQ_LDS_BANK_CONFLICT ~1.2e7 = b64/b128 bank floor (ignore).

#define W 512
#define H 512
#define NIMG 96
#define TX 64
#define CHUNK 16
#define STRIP 128
#define NITER 8            // STRIP/CHUNK
#define BUF 26             // s_q circular rows
#define PADH 66            // uint2 row stride: 528 B -> 4-way b64 floor on store/read
#define NSLOT 128
#define RAWB 10240         // raw staging: 2 tensors * 16 rows * 320 B

typedef __fp16 h2 __attribute__((ext_vector_type(2)));   // matches cvt_pkrtz return

// symmetric gaussian: gw[k] == gwu[k<6 ? k : 10-k], k compile-time when unrolled
#define GW(k)  gwu[(k) < 6 ? (k) : 10 - (k)]
#define GWH(k) gwh[(k) < 6 ? (k) : 10 - (k)]

#define GLL(sp, dp) __builtin_amdgcn_global_load_lds(                         \
    (const __attribute__((address_space(1))) void*)(sp),                      \
    (__attribute__((address_space(3))) void*)(dp), 16, 0, 0)

__global__ void hybrid_init(double* __restrict__ ws) {
    int t = threadIdx.x;
    if (t < 2 * NSLOT) ws[t] = 0.0;
}

__global__ __launch_bounds__(256, 4) void hybrid_main(
    const float* __restrict__ pred, const float* __restrict__ targ,
    double* __restrict__ ws)
{
    __shared__ uint2 s_q[BUF][PADH];              // 13728 B: hconv results (fp16 x4)
    __shared__ __align__(16) char s_raw[RAWB];    // 10240 B: staged raw pixels

    const int tid = threadIdx.x;
    const float* __restrict__ pp = pred + (size_t)blockIdx.z * (H * W);
    const float* __restrict__ tp = targ + (size_t)blockIdx.z * (H * W);
    const int xbase = blockIdx.x * TX;
    const int Y0 = blockIdx.y * STRIP;
    const int xb8 = xbase - 8;         // raw window = [xb8, xb8+80)

    // Normalized 1D Gaussian, 6 unique weights (symmetric), f32 like ref
    float gwu[6];
    __fp16 gwh[6];
    {
        float s = 0.f;
#pragma unroll
        for (int k = 0; k < 6; ++k) {
            float d = (float)(k - 5);
            gwu[k] = expf(-d * d / 4.5f);   // 2*sigma^2 = 4.5
            s += (k < 5) ? 2.f * gwu[k] : gwu[k];
        }
        float inv = 1.f / s;
#pragma unroll
        for (int k = 0; k < 6; ++k) { gwu[k] *= inv; gwh[k] = (__fp16)gwu[k]; }
    }

    // explicit ranges so clang's value-range analysis folds wrap checks
    const int hrow_i = (tid >> 4) & 15;   // 0..15 : hconv row-in-chunk
    const int g      = tid & 15;          // 4-col group
    const int c0     = g * 4;
    const int A0     = xbase + c0 - 8;    // 20-px window [A0, A0+20)
    const bool inX   = (A0 >= 0) && (A0 + 20 <= W);

    const int wv     = (tid >> 6) & 3;    // wave 0..3
    const int cc     = tid & 63;          // vconv column
    const int lane16 = (tid & 63) * 16;

    // slow-path needed only where reads could run past the allocation end
    const bool tb = ((int)blockIdx.z == NIMG - 1) && ((int)blockIdx.y == (H / STRIP) - 1);

    float mse_local = 0.f, ssim_local = 0.f;

    // ---- chunk-invariant DMA addressing (per wave: m = wv, wv+4, [wv+8]) ----
    auto mkaddr = [&](int m, const float*& sp, const char*& dp) {
        const int t  = (m >= 5);
        const int mm = m - 5 * t;
        const int oo = mm * 1024 + lane16;
        const int r  = oo / 320;
        const int cb = oo - r * 320;
        int col = xb8 + (cb >> 2);
        col = col < 0 ? 0 : (col > W - 4 ? W - 4 : col);
        sp = (t ? tp : pp) + (size_t)(Y0 + 5 + r) * W + col;
        dp = s_raw + m * 1024;          // wave-uniform base
    };
    const float *sA, *sB, *sC = nullptr;
    const char  *dA, *dB, *dC = nullptr;
    mkaddr(wv, sA, dA);
    mkaddr(wv + 4, sB, dB);
    const bool hasC = (wv + 8) < 10;
    if (hasC) mkaddr(wv + 8, sC, dC);

    auto issue_fast = [&]() {          // advance-only: 2-3 DMA + ptr bumps
        GLL(sA, dA); sA += CHUNK * W;
        GLL(sB, dB); sB += CHUNK * W;
        if (hasC) { GLL(sC, dC); sC += CHUNK * W; }
    };

    auto issue_slow = [&](int kc) {    // y-clamped general path, tail blocks only
        const int gybase = Y0 + 5 + CHUNK * kc;
#pragma unroll
        for (int m0 = 0; m0 < 12; m0 += 4) {
            const int m = wv + m0;
            if (m < 10) {
                const int t  = (m >= 5);
                const int oo = (m - 5 * t) * 1024 + lane16;
                const int r  = oo / 320;
                const int cb = oo - r * 320;
                int gy = gybase + r; if (gy > H - 1) gy = H - 1;
                int col = xb8 + (cb >> 2);
                col = col < 0 ? 0 : (col > W - 4 ? W - 4 : col);
                const float* src = (t ? tp : pp) + gy * W + col;
                GLL(src, s_raw + m * 1024);
            }
        }
    };

    // ---- read this thread's 20-px window from s_raw (+ x-edge masks) ----
    auto read_staged = [&](float* xa, float* ya) {
#pragma unroll
        for (int v = 0; v < 5; ++v) {
            const int off = hrow_i * 320 + (g + v) * 16;
            float4 a = *(const float4*)&s_raw[off];
            float4 b = *(const float4*)&s_raw[RAWB / 2 + off];
            xa[4*v+0]=a.x; xa[4*v+1]=a.y; xa[4*v+2]=a.z; xa[4*v+3]=a.w;
            ya[4*v+0]=b.x; ya[4*v+1]=b.y; ya[4*v+2]=b.z; ya[4*v+3]=b.w;
        }
        if (!inX) {                      // only blocks x=0,7 ever diverge here
#pragma unroll
            for (int j = 0; j < 20; ++j) {
                if ((unsigned)(A0 + j) >= (unsigned)W) { xa[j] = 0.f; ya[j] = 0.f; }
            }
        }
    };

    // ---- MSE (raw f32) + clip + horizontal 11-tap in PACKED FP16 -> s_q ----
    // Accumulators are the stored format: store = bit_cast, no cvt.
    auto hconv_store = [&](const float* xa, const float* ya, int slot, bool own) {
        if (own) {
#pragma unroll
            for (int c = 0; c < 4; ++c) {
                float d = xa[8 + c] - ya[8 + c];
                mse_local = fmaf(d, d, mse_local);
            }
        }
        h2 a01[4], a2x[4];               // (mu_x,mu_y), (E[x2+y2],E[xy]) pairs
#pragma unroll
        for (int i = 0; i < 4; ++i) {
            a01[i] = (h2)(__fp16)0.f;
            a2x[i] = (h2)(__fp16)0.f;
        }
#pragma unroll
        for (int j = 0; j < 14; ++j) {        // window positions 3..16
            float cx = __builtin_amdgcn_fmed3f(xa[3 + j], 0.f, 1.f);
            float yv = ya[3 + j];
            float s2 = fmaf(yv, yv, cx * cx); // x^2 + y^2
            float xy = cx * yv;
            h2 p0 = __builtin_amdgcn_cvt_pkrtz(cx, yv);
            h2 p1 = __builtin_amdgcn_cvt_pkrtz(s2, xy);
#pragma unroll
            for (int i = 0; i < 4; ++i) {
                int k = j - i;
                if (k >= 0 && k < 11) {
                    __fp16 w = GWH(k);
                    h2 w2; w2.x = w; w2.y = w;
                    a01[i] = w2 * p0 + a01[i];   // v_pk_fma_f16
                    a2x[i] = w2 * p1 + a2x[i];   // v_pk_fma_f16
                }
            }
        }
#pragma unroll
        for (int i = 0; i < 4; ++i) {
            uint2 u;
            u.x = __builtin_bit_cast(unsigned int, a01[i]);
            u.y = __builtin_bit_cast(unsigned int, a2x[i]);
            s_q[slot][c0 + i] = u;                              // ds_write_b64
        }
    };

    // ---- Prologue: DMA chunk 0; direct-load hconv of ext rows 0..9 ----
    if (tb) issue_slow(0); else issue_fast();
    if (hrow_i < 10) {
        float xa[20], ya[20];
        const int gy = Y0 - 5 + hrow_i;
        if (gy >= 0 && gy < H) {
            const float* __restrict__ px = pp + (size_t)gy * W;
            const float* __restrict__ py = tp + (size_t)gy * W;
            if (inX) {
                const float4* qx = (const float4*)(px + A0);
                const float4* qy = (const float4*)(py + A0);
#pragma unroll
                for (int v = 0; v < 5; ++v) {
                    float4 a = qx[v], b = qy[v];
                    xa[4*v+0]=a.x; xa[4*v+1]=a.y; xa[4*v+2]=a.z; xa[4*v+3]=a.w;
                    ya[4*v+0]=b.x; ya[4*v+1]=b.y; ya[4*v+2]=b.z; ya[4*v+3]=b.w;
                }
            } else {
#pragma unroll
                for (int j = 0; j < 20; ++j) {
                    int col = A0 + j;
                    bool ok = (col >= 0) && (col < W);
                    xa[j] = ok ? px[col] : 0.f;
                    ya[j] = ok ? py[col] : 0.f;
                }
            }
        } else {
#pragma unroll
            for (int j = 0; j < 20; ++j) { xa[j] = 0.f; ya[j] = 0.f; }
        }
        hconv_store(xa, ya, hrow_i, hrow_i >= 5);
    }
    __syncthreads();   // drains chunk-0 DMA; prologue s_q visible

    const float C1 = 1e-4f, C2 = 9e-4f;

#pragma unroll
    for (int k = 0; k < NITER; ++k) {
        // ---- hconv k from staged s_raw: ext rows 16k+10 .. 16k+25 ----
        {
            const int ext = CHUNK * k + 10 + hrow_i;
            const int gy  = Y0 - 5 + ext;                // >= 5, can exceed H-1
            const int hb  = (10 + CHUNK * k) % BUF;      // compile-time
            int slot;
            if (hb + 15 >= BUF) {                        // compile-time guard
                slot = hb + hrow_i; if (slot >= BUF) slot -= BUF;
            } else {
                slot = hb + hrow_i;                      // provably in range
            }
            if (gy < H) {
                float xa[20], ya[20];
                read_staged(xa, ya);
                hconv_store(xa, ya, slot, ext <= STRIP + 4);
            } else {                                     // OOB row: zeros, no conv
                uint2 z; z.x = 0u; z.y = 0u;
#pragma unroll
                for (int i = 0; i < 4; ++i) s_q[slot][c0 + i] = z;
            }
        }
        __syncthreads();   // A: s_q visible; all s_raw reads complete

        // ---- DMA next chunk into s_raw; latency hides under vconv ----
        if (k + 1 < NITER) { if (tb) issue_slow(k + 1); else issue_fast(); }

        // ---- vconv k: packed fp16 accumulation (v_pk_fma_f16, zero movs) ----
        {
            const int vb = (CHUNK * k) % BUF;            // compile-time
            const int r4 = 4 * wv;                       // 0,4,8,12 (range known)
            h2 a01[4], a2x[4];           // (mu_x,mu_y), (E[x2+y2],E[xy]) pairs
#pragma unroll
            for (int i = 0; i < 4; ++i) {
                a01[i] = (h2)(__fp16)0.f;
                a2x[i] = (h2)(__fp16)0.f;
            }
#pragma unroll
            for (int j = 0; j < 14; ++j) {
                const int sj = vb + j;                   // compile-time
                int s;
                if (sj + 12 >= BUF) {                    // compile-time guard
                    s = sj + r4; if (s >= BUF) s -= BUF;
                } else {
                    s = sj + r4;                         // provably in range
                }
                uint2 u = s_q[s][cc];                    // ds_read_b64
                h2 lo = __builtin_bit_cast(h2, u.x);
                h2 hi = __builtin_bit_cast(h2, u.y);
#pragma unroll
                for (int i = 0; i < 4; ++i) {
                    int kk = j - i;
                    if (kk >= 0 && kk < 11) {
                        __fp16 w = GWH(kk);
                        h2 w2; w2.x = w; w2.y = w;
                        a01[i] = w2 * lo + a01[i];       // v_pk_fma_f16
                        a2x[i] = w2 * hi + a2x[i];       // v_pk_fma_f16
                    }
                }
            }
#pragma unroll
            for (int i = 0; i < 4; ++i) {
                float mux = (float)a01[i].x, muy = (float)a01[i].y;
                float es  = (float)a2x[i].x, exy = (float)a2x[i].y;
                float mu_x2 = mux * mux, mu_y2 = muy * muy, mu_xy = mux * muy;
                float ssum = es - mu_x2 - mu_y2;         // sigma_x2 + sigma_y2
                float sxy  = exy - mu_xy;
                float num = (2.f*mu_xy + C1) * (2.f*sxy + C2);
                float den = (mu_x2 + mu_y2 + C1) * (ssum + C2);
                ssim_local = fmaf(num, __builtin_amdgcn_rcpf(den), ssim_local);
            }
        }
        __syncthreads();   // B: drains DMA (s_raw = chunk k+1); s_q reads done
    }

    // ---- Per-wave reduction + spread f64 atomics ----
    float m = mse_local, s2 = ssim_local;
#pragma unroll
    for (int off = 32; off; off >>= 1) {
        m  += __shfl_down(m, off);
        s2 += __shfl_down(s2, off);
    }
    if ((tid & 63) == 0) {
        int flat = blockIdx.x + 8 * (blockIdx.y + 4 * blockIdx.z);
        int slot = (flat * 4 + wv) & (NSLOT - 1);
        atomicAdd(&ws[slot], (double)m);
        atomicAdd(&ws[NSLOT + slot], (double)s2);
    }
}

__global__ void hybrid_fin(const double* __restrict__ ws, float* __restrict__ out) {
    int t = threadIdx.x;  // 64 threads
    double m = ws[t] + ws[t + 64];
    double s = ws[NSLOT + t] + ws[NSLOT + t + 64];
#pragma unroll
    for (int off = 32; off; off >>= 1) {
        m += __shfl_down(m, off);
        s += __shfl_down(s, off);
    }
    if (t == 0) {
        const double N = (double)NIMG * H * W;
        double mse  = m / N;
        double ssim = s / N;
        out[0] = (float)(0.8 * mse + 0.2 * (1.0 - ssim));
    }
}

extern "C" void kernel_launch(void* const* d_in, const int* in_sizes, int n_in,
                              void* d_out, int out_size, void* d_ws, size_t ws_size,
                              hipStream_t stream) {
    const float* pred = (const float*)d_in[0];
    const float* targ = (const float*)d_in[1];
    double* ws = (double*)d_ws;
    float* out = (float*)d_out;

    hybrid_init<<<1, 256, 0, stream>>>(ws);
    dim3 grid(W / TX, H / STRIP, NIMG);
    hybrid_main<<<grid, dim3(256), 0, stream>>>(pred, targ, ws);
    hybrid_fin<<<1, 64, 0, stream>>>(ws, out);
}